// Round 1
// baseline (142.305 us; speedup 1.0000x reference)
//
#include <hip/hip_runtime.h>
#include <hip/hip_bf16.h>

// Problem constants (fixed by reference setup: N=4096, D=512, C=100)
#define D_DIM 512
#define KSTEPS 16          // 512 / 32 (K per MFMA)
#define BM 64              // rows per block = 4 waves x 16 rows
#define BN 64              // columns per LDS tile
#define GRIDY 4            // column chunks across grid

typedef __bf16 bf16x8 __attribute__((ext_vector_type(8)));
typedef float  f32x4  __attribute__((ext_vector_type(4)));

__device__ __forceinline__ unsigned short f2bf_rne(float x) {
    unsigned int u = __float_as_uint(x);
    u += 0x7FFFu + ((u >> 16) & 1u);
    return (unsigned short)(u >> 16);
}

// rows [0,N): inst_embed -> instb ; rows [N,2N): proxy -> proxyb
__global__ __launch_bounds__(128) void normalize_rows(
    const float* __restrict__ inst, const float* __restrict__ proxy,
    unsigned short* __restrict__ instb, unsigned short* __restrict__ proxyb, int N)
{
    int row = blockIdx.x;
    const float* src;
    unsigned short* dst;
    if (row < N) { src = inst  + (size_t)row * D_DIM;        dst = instb  + (size_t)row * D_DIM; }
    else         { src = proxy + (size_t)(row - N) * D_DIM;  dst = proxyb + (size_t)(row - N) * D_DIM; }
    int t = threadIdx.x;                       // 128 threads x float4 = 512 elems
    float4 v = ((const float4*)src)[t];
    float ss = v.x*v.x + v.y*v.y + v.z*v.z + v.w*v.w;
    #pragma unroll
    for (int off = 32; off > 0; off >>= 1) ss += __shfl_down(ss, off, 64);
    __shared__ float wss[2];
    if ((t & 63) == 0) wss[t >> 6] = ss;
    __syncthreads();
    float inv = 1.0f / fmaxf(sqrtf(wss[0] + wss[1]), 1e-8f);
    ushort4 o;
    o.x = f2bf_rne(v.x * inv); o.y = f2bf_rne(v.y * inv);
    o.z = f2bf_rne(v.z * inv); o.w = f2bf_rne(v.w * inv);
    ((ushort4*)dst)[t] = o;
}

// Fused: sim tile via MFMA -> exp -> mask gather -> row-sum accumulate.
// Logical rows [0,N) = proxy rows (p2i), [N,2N) = inst rows (i2i). B is always inst.
// nd layout: [p2i_num | p2i_den | i2i_num | i2i_den], each N floats, pre-zeroed.
__global__ __launch_bounds__(256, 2) void fused_scores(
    const unsigned short* __restrict__ instb,
    const unsigned short* __restrict__ proxyb,
    const float* __restrict__ negmask,   // [C, N]
    const int*  __restrict__ labels,     // [N]
    const float* __restrict__ temp_p,
    const float* __restrict__ margin_p,
    float* __restrict__ nd,
    int N, int colsPerBlock)
{
    __shared__ unsigned short Bt[BN * D_DIM];   // 64 KB, xor-swizzled 16B chunks

    const int tid  = threadIdx.x;
    const int lane = tid & 63;
    const int wave = tid >> 6;      // 0..3
    const int quad = lane >> 4;     // 0..3
    const int l16  = lane & 15;

    const int Rbase  = blockIdx.x * BM + wave * 16;   // wave's 16 logical rows
    const bool isP2I = (Rbase < N);
    const unsigned short* Aptr = isP2I ? (proxyb + (size_t)Rbase * D_DIM)
                                       : (instb  + (size_t)(Rbase - N) * D_DIM);
    const int rowLocal = isP2I ? Rbase : (Rbase - N);

    const float temp  = *temp_p;
    const float scale = 1.44269504088896340736f / temp;   // log2(e)/t
    const float bias  = -(*margin_p) * scale;

    // A slab resident in registers: MFMA A-layout A[m=lane&15][k=quad*8+j]
    bf16x8 Afrag[KSTEPS];
    {
        const unsigned short* arow = Aptr + (size_t)l16 * D_DIM + quad * 8;
        #pragma unroll
        for (int ks = 0; ks < KSTEPS; ks++)
            Afrag[ks] = *(const bf16x8*)(arow + ks * 32);
    }

    // labels for this lane's 4 output rows (C/D layout: row = quad*4 + reg)
    int lab[4];
    #pragma unroll
    for (int r = 0; r < 4; r++) lab[r] = labels[rowLocal + quad * 4 + r];

    float numAcc[4] = {0.f,0.f,0.f,0.f};
    float denAcc[4] = {0.f,0.f,0.f,0.f};

    const int j0base = blockIdx.y * colsPerBlock;
    for (int jt = 0; jt < colsPerBlock; jt += BN) {
        const int j0 = j0base + jt;
        __syncthreads();   // protect previous tile's reads
        // Stage B tile: 64 rows x 512 bf16, 16B chunks xor-swizzled by row&7
        #pragma unroll
        for (int it = 0; it < (BN * (D_DIM/8)) / 256; it++) {
            int c   = tid + it * 256;
            int br  = c >> 6;          // row in tile
            int ch  = c & 63;          // 16B chunk within row
            int chs = ch ^ (br & 7);
            float4 v = ((const float4*)(instb + (size_t)(j0 + br) * D_DIM))[ch];
            *(float4*)&Bt[br * D_DIM + chs * 8] = v;
        }
        __syncthreads();

        f32x4 acc[4] = {};   // 4 column groups of 16
        #pragma unroll
        for (int ks = 0; ks < KSTEPS; ks++) {
            #pragma unroll
            for (int cg = 0; cg < 4; cg++) {
                int rB  = cg * 16 + l16;                 // B column = LDS row
                int chs = (ks * 4 + quad) ^ (rB & 7);
                bf16x8 b = *(const bf16x8*)&Bt[rB * D_DIM + chs * 8];
                acc[cg] = __builtin_amdgcn_mfma_f32_16x16x32_bf16(Afrag[ks], b, acc[cg], 0, 0, 0);
            }
        }

        // Epilogue: zone = exp2(sim*scale + bias); accumulate den and masked num
        #pragma unroll
        for (int cg = 0; cg < 4; cg++) {
            int j = j0 + cg * 16 + l16;
            #pragma unroll
            for (int r = 0; r < 4; r++) {
                float zone = exp2f(acc[cg][r] * scale + bias);
                denAcc[r] += zone;
                float m = negmask[(size_t)lab[r] * N + j];
                numAcc[r] += zone * m;
            }
        }
    }

    // Reduce across the 16 lanes (l16) sharing each output row, then atomicAdd
    #pragma unroll
    for (int r = 0; r < 4; r++) {
        float n = numAcc[r], d = denAcc[r];
        #pragma unroll
        for (int off = 8; off > 0; off >>= 1) {
            n += __shfl_down(n, off, 16);
            d += __shfl_down(d, off, 16);
        }
        if (l16 == 0) {
            float* numArr = nd + (isP2I ? 0 : 2 * N);
            float* denArr = numArr + N;
            atomicAdd(&numArr[rowLocal + quad * 4 + r], n);
            atomicAdd(&denArr[rowLocal + quad * 4 + r], d);
        }
    }
}

__global__ __launch_bounds__(256) void loss_reduce(
    const float* __restrict__ nd, const float* __restrict__ temp_p,
    float* __restrict__ out, int N)
{
    const float t = *temp_p;
    float s = 0.f;
    for (int i = threadIdx.x; i < N; i += 256) {
        s -= logf(t * nd[i]         / nd[N + i]);       // p2i
        s -= logf(t * nd[2 * N + i] / nd[3 * N + i]);   // i2i
    }
    #pragma unroll
    for (int off = 32; off > 0; off >>= 1) s += __shfl_down(s, off, 64);
    __shared__ float wss[4];
    if ((threadIdx.x & 63) == 0) wss[threadIdx.x >> 6] = s;
    __syncthreads();
    if (threadIdx.x == 0) out[0] = (wss[0] + wss[1] + wss[2] + wss[3]) / (float)N;
}

extern "C" void kernel_launch(void* const* d_in, const int* in_sizes, int n_in,
                              void* d_out, int out_size, void* d_ws, size_t ws_size,
                              hipStream_t stream)
{
    const float* inst     = (const float*)d_in[0];
    const float* proxy    = (const float*)d_in[1];
    const float* negmask  = (const float*)d_in[2];
    const int*   labels   = (const int*)d_in[3];
    const float* temp_p   = (const float*)d_in[4];
    const float* margin_p = (const float*)d_in[5];
    float* out = (float*)d_out;

    const int N = in_sizes[3];    // 4096 (D fixed at 512 per reference)

    unsigned short* instb  = (unsigned short*)d_ws;
    unsigned short* proxyb = instb + (size_t)N * D_DIM;
    float* nd = (float*)(proxyb + (size_t)N * D_DIM);

    hipMemsetAsync(nd, 0, sizeof(float) * 4 * N, stream);
    normalize_rows<<<2 * N, 128, 0, stream>>>(inst, proxy, instb, proxyb, N);
    dim3 grid(2 * N / BM, GRIDY);
    fused_scores<<<grid, 256, 0, stream>>>(instb, proxyb, negmask, labels,
                                           temp_p, margin_p, nd, N, N / GRIDY);
    loss_reduce<<<1, 256, 0, stream>>>(nd, temp_p, out, N);
}